// Round 12
// baseline (2112.313 us; speedup 1.0000x reference)
//
#include <hip/hip_runtime.h>
#include <cstdint>

typedef __attribute__((ext_vector_type(8))) short short8;
typedef __attribute__((ext_vector_type(4))) float f32x4;
typedef __attribute__((ext_vector_type(2))) float f32x2;

#define TPB  64      // ONE wave per block -> no barriers at all
#define MB   16      // batch rows per block
#define HS   50      // hidden size
#define HSTR 72      // h row stride in halves (144B, 16B-aligned)
#define XSTR 68      // x row stride in u32 (272B, 16B-aligned)
#define L2E  1.4426950408889634f
#define L2E2 2.8853900817779268f

__device__ __forceinline__ float ex2(float x) {
#if __has_builtin(__builtin_amdgcn_exp2f)
  return __builtin_amdgcn_exp2f(x);
#else
  float r; asm("v_exp_f32 %0, %1" : "=v"(r) : "v"(x)); return r;
#endif
}
__device__ __forceinline__ float rcp_(float x) {
#if __has_builtin(__builtin_amdgcn_rcpf)
  return __builtin_amdgcn_rcpf(x);
#else
  float r; asm("v_rcp_f32 %0, %1" : "=v"(r) : "v"(x)); return r;
#endif
}
__device__ __forceinline__ unsigned short bf16_rne(float f) {
  unsigned r;
  asm("v_cvt_pk_bf16_f32 %0, %1, %2" : "=v"(r) : "v"(f), "v"(f));
  return (unsigned short)r;
}
__device__ __forceinline__ unsigned cvtpk2(float a, float b) {
  unsigned r;
  asm("v_cvt_pk_bf16_f32 %0, %1, %2" : "=v"(r) : "v"(a), "v"(b));
  return r;   // lo = a, hi = b
}
__device__ __forceinline__ float bf16f(unsigned short h) {
  union { unsigned u; float f; } v; v.u = ((unsigned)h) << 16; return v.f;
}
__device__ __forceinline__ unsigned packx(float f) {
  unsigned short hi = bf16_rne(f);
  unsigned short lo = bf16_rne(f - bf16f(hi));
  return (unsigned)hi | ((unsigned)lo << 16);
}
// column swizzle (identical helper on every read and write)
__device__ __forceinline__ int swcol(int row, int col) {
  return (((col >> 3) ^ ((row >> 2) & 3)) << 3) | (col & 7);
}

// Wave-autonomous LSTM: one wave owns 16 batches for all T steps.
//   Per step: gates^T[256 n][16 b] = W[256 n][64 k] * hT[64 k][16 b]
//   via 4 g-tiles (A = W frags for chunk g, registers; B = h^T from LDS,
//   SHARED by all g). k 0..49 = h(t-1); k50=xv_hi k51=xv_lo k52=xv_hi
//   k53=1 k54=1 live as real LDS cols written each step (no reg injection);
//   W frag1 slots pair them: w_ih_hi, w_ih_hi, w_ih_lo, bias_hi, bias_lo.
//   Single h buffer: step-t reads precede step-t writes in program order
//   (one wave, in-order DS). No __syncthreads anywhere.
//   g=3 tile: r=2,3 all-pad -> skip ELEM half; h-write masked to lhi==0
//   (b32 covers j=48,49 only) so pad lanes can't corrupt x/bias cols.
__global__ __launch_bounds__(TPB, 1)
void lstm_solo(const float* __restrict__ x,
               const float* __restrict__ w_ih,
               const float* __restrict__ w_hh,
               const float* __restrict__ b_ih,
               const float* __restrict__ b_hh,
               const float* __restrict__ w_fc,
               const float* __restrict__ b_fc,
               float* __restrict__ out, int T)
{
  __shared__ __attribute__((aligned(16))) unsigned short h_lds[MB][HSTR];
  __shared__ __attribute__((aligned(16))) unsigned x_lds[2][MB][XSTR];

  const int lane = threadIdx.x;    // 0..63
  const int l15  = lane & 15;
  const int lhi  = lane >> 4;      // 0..3
  const int b0   = blockIdx.x * MB;

  // ---- static W-fragments for ALL 4 j-chunks (A-operand), 128 VGPR ----
  short8 Wh[4][4][2];
  #pragma unroll
  for (int g = 0; g < 4; ++g) {
    const int j = g * 16 + l15;
    const bool jv = (j < HS);
    #pragma unroll
    for (int s = 0; s < 4; ++s) {
      const float sc = (s == 2) ? L2E2 : L2E;
      float wsc = 0.f, bsc = 0.f;
      if (jv) {
        int row = s * HS + j;
        wsc = w_ih[row] * sc;
        bsc = (b_ih[row] + b_hh[row]) * sc;
      }
      const unsigned short wh = bf16_rne(wsc);
      const unsigned short wl = bf16_rne(wsc - bf16f(wh));
      const unsigned short bh = bf16_rne(bsc);
      const unsigned short bl = bf16_rne(bsc - bf16f(bh));
      #pragma unroll
      for (int i = 0; i < 8; ++i) {         // frag 0: k = 0..31
        int k = lhi * 8 + i;
        Wh[g][s][0][i] = (short)(jv ? bf16_rne(w_hh[(s * HS + j) * HS + k] * sc) : 0);
      }
      #pragma unroll
      for (int i = 0; i < 8; ++i) {         // frag 1: k = 32..63
        int k = 32 + lhi * 8 + i;
        unsigned short hv = 0;
        if (jv) {
          if (k < HS)                  hv = bf16_rne(w_hh[(s * HS + j) * HS + k] * sc);
          else if (k == 50 || k == 51) hv = wh;
          else if (k == 52)            hv = wl;
          else if (k == 53)            hv = bh;
          else if (k == 54)            hv = bl;
        }
        Wh[g][s][1][i] = (short)hv;
      }
    }
  }

  unsigned short* hs = &h_lds[0][0];

  // ---- init (single wave: no barriers; DS in-order) ----
  for (int idx = lane; idx < MB * HSTR; idx += TPB) hs[idx] = 0;

  const int keyr  = (l15 >> 2) & 3;
  const int offA0 = l15 * HSTR + ((lhi ^ keyr) << 3);         // B frag0
  const int offA1 = l15 * HSTR + (((lhi + 4) ^ keyr) << 3);   // B frag1
  const int offX  = l15 * HSTR + ((6 ^ keyr) << 3);           // block of cols 48..55

  if (lane < 16)
    hs[offX + 6] = 0x3F80;   // col 54 = 1.0 (pairs bias_lo), static

  // stage x chunk 0: lane covers row lane>>2, 16 steps starting (lane&3)*16
  {
    const int bb = lane >> 2, base = (lane & 3) * 16;
    const float* xr = x + (size_t)(b0 + bb) * T + base;
    #pragma unroll
    for (int q = 0; q < 4; ++q) {
      const f32x4 v = *(const f32x4*)(xr + q * 4);
      uint4 up;
      up.x = packx(v[0]); up.y = packx(v[1]); up.z = packx(v[2]); up.w = packx(v[3]);
      *(uint4*)&x_lds[0][bb][base + q * 4] = up;
    }
  }

  // cell states (scaled c~ = 2*log2e*c) per g-tile
  f32x2 cA[4] = {{0.f,0.f},{0.f,0.f},{0.f,0.f},{0.f,0.f}};
  f32x2 cB[3] = {{0.f,0.f},{0.f,0.f},{0.f,0.f}};
  f32x4 xf0 = {0,0,0,0}, xf1 = {0,0,0,0}, xf2 = {0,0,0,0}, xf3 = {0,0,0,0};
  const int nch = T >> 6;   // T = 2048

  // elementwise core (identical arithmetic to round-7/10 known-good)
  auto ELEM = [&](f32x2 ai, f32x2 af, f32x2 ag, f32x2 ao, f32x2& c2) -> f32x2 {
    f32x2 u, v, w, z, q, rD, r3, vm1;
    u[0] = ex2(-ai[0]); u[1] = ex2(-ai[1]);
    v[0] = ex2( ag[0]); v[1] = ex2( ag[1]);
    w[0] = ex2(-af[0]); w[1] = ex2(-af[1]);
    z[0] = ex2(-ao[0]); z[1] = ex2(-ao[1]);
    f32x2 t1 = (u + 1.f) * (v + 1.f);
    f32x2 wp = w + 1.f;
    f32x2 D  = t1 * wp;
    rD[0] = rcp_(D[0]); rD[1] = rcp_(D[1]);
    vm1[0] = fmaf(v[0], L2E2, -L2E2);
    vm1[1] = fmaf(v[1], L2E2, -L2E2);
    f32x2 num = c2 * t1 + vm1 * wp;
    f32x2 cn = num * rD;
    cn[0] = fminf(fmaxf(cn[0], -86.f), 86.f);
    cn[1] = fminf(fmaxf(cn[1], -86.f), 86.f);
    c2 = cn;
    q[0] = ex2(cn[0]); q[1] = ex2(cn[1]);
    f32x2 t3 = (z + 1.f) * (q + 1.f);
    r3[0] = rcp_(t3[0]); r3[1] = rcp_(t3[1]);
    return (q - 1.f) * r3;
  };

  auto STEP = [&](const unsigned* xrow, int slot) {
    // write x/bias cols for THIS step (before B-frag reads; in-order DS)
    if (lane < 16) {
      const unsigned xp = xrow[slot];                 // {xhi | xlo<<16}
      *(unsigned*)(hs + offX + 2) = xp;                              // cols 50,51
      *(unsigned*)(hs + offX + 4) = (xp & 0xFFFFu) | 0x3F800000u;    // cols 52,53
    }
    // B-operand (h^T + x/bias cols), shared by all 4 g-tiles
    const short8 B0 = *(const short8*)(hs + offA0);
    const short8 B1 = *(const short8*)(hs + offA1);

    #pragma unroll
    for (int g = 0; g < 4; ++g) {
      f32x4 a0 = __builtin_amdgcn_mfma_f32_16x16x32_bf16(Wh[g][0][0], B0,
                     (f32x4){0.f,0.f,0.f,0.f}, 0, 0, 0);
      f32x4 a1 = __builtin_amdgcn_mfma_f32_16x16x32_bf16(Wh[g][1][0], B0,
                     (f32x4){0.f,0.f,0.f,0.f}, 0, 0, 0);
      f32x4 a2 = __builtin_amdgcn_mfma_f32_16x16x32_bf16(Wh[g][2][0], B0,
                     (f32x4){0.f,0.f,0.f,0.f}, 0, 0, 0);
      f32x4 a3 = __builtin_amdgcn_mfma_f32_16x16x32_bf16(Wh[g][3][0], B0,
                     (f32x4){0.f,0.f,0.f,0.f}, 0, 0, 0);
      a0 = __builtin_amdgcn_mfma_f32_16x16x32_bf16(Wh[g][0][1], B1, a0, 0, 0, 0);
      a1 = __builtin_amdgcn_mfma_f32_16x16x32_bf16(Wh[g][1][1], B1, a1, 0, 0, 0);
      a2 = __builtin_amdgcn_mfma_f32_16x16x32_bf16(Wh[g][2][1], B1, a2, 0, 0, 0);
      a3 = __builtin_amdgcn_mfma_f32_16x16x32_bf16(Wh[g][3][1], B1, a3, 0, 0, 0);

      const int offW = l15 * HSTR +
          ((((g * 2 + (lhi >> 1)) ^ keyr) << 3)) + (lhi & 1) * 4;

      f32x2 hA = ELEM((f32x2){a0[0], a0[1]}, (f32x2){a1[0], a1[1]},
                      (f32x2){a2[0], a2[1]}, (f32x2){a3[0], a3[1]}, cA[g]);
      if (g < 3) {
        f32x2 hB = ELEM((f32x2){a0[2], a0[3]}, (f32x2){a1[2], a1[3]},
                        (f32x2){a2[2], a2[3]}, (f32x2){a3[2], a3[3]}, cB[g]);
        uint2 hwv;
        hwv.x = cvtpk2(hA[0], hA[1]);
        hwv.y = cvtpk2(hB[0], hB[1]);
        *(uint2*)(hs + offW) = hwv;          // 4 consecutive j at row b=l15
      } else {
        // j=48,49 only (lhi==0); other lanes are pad and MUST NOT write
        // (cols 50+ hold live x/bias data)
        if (lhi == 0)
          *(unsigned*)(hs + offW) = cvtpk2(hA[0], hA[1]);
      }
    }
  };

  for (int ch = 0; ch < nch; ++ch) {
    const unsigned* xrow = &x_lds[ch & 1][l15][0];
    int slot = 0;
    #pragma unroll 1
    for (int i = 0; i < 16; ++i) STEP(xrow, slot++);
    if (ch + 1 < nch) {                    // issue next-chunk global loads
      const float* xr = x + (size_t)(b0 + (lane >> 2)) * T + (ch + 1) * 64 + (lane & 3) * 16;
      xf0 = *(const f32x4*)(xr);
      xf1 = *(const f32x4*)(xr + 4);
      xf2 = *(const f32x4*)(xr + 8);
      xf3 = *(const f32x4*)(xr + 12);
    }
    #pragma unroll 1
    for (int i = 0; i < 28; ++i) STEP(xrow, slot++);
    if (ch + 1 < nch) {                    // pack + write next chunk
      const int bb = lane >> 2, base = (lane & 3) * 16;
      uint4 u0, u1, u2, u3;
      u0.x = packx(xf0[0]); u0.y = packx(xf0[1]); u0.z = packx(xf0[2]); u0.w = packx(xf0[3]);
      u1.x = packx(xf1[0]); u1.y = packx(xf1[1]); u1.z = packx(xf1[2]); u1.w = packx(xf1[3]);
      u2.x = packx(xf2[0]); u2.y = packx(xf2[1]); u2.z = packx(xf2[2]); u2.w = packx(xf2[3]);
      u3.x = packx(xf3[0]); u3.y = packx(xf3[1]); u3.z = packx(xf3[2]); u3.w = packx(xf3[3]);
      unsigned* dst = &x_lds[(ch + 1) & 1][bb][base];
      *(uint4*)(dst)      = u0;
      *(uint4*)(dst + 4)  = u1;
      *(uint4*)(dst + 8)  = u2;
      *(uint4*)(dst + 12) = u3;
    }
    #pragma unroll 1
    for (int i = 0; i < 20; ++i) STEP(xrow, slot++);
  }

  // fc head on final h (cols 0..49 only; 50+ hold x/bias junk)
  if (lane < 16) {
    float s = 0.f;
    for (int jj = 0; jj < HS; ++jj)
      s = fmaf(bf16f(hs[lane * HSTR + swcol(lane, jj)]), w_fc[jj], s);
    out[b0 + lane] = s + b_fc[0];
  }
}

extern "C" void kernel_launch(void* const* d_in, const int* in_sizes, int n_in,
                              void* d_out, int out_size, void* d_ws, size_t ws_size,
                              hipStream_t stream) {
  const float* x    = (const float*)d_in[0];
  const float* w_ih = (const float*)d_in[1];
  const float* w_hh = (const float*)d_in[2];
  const float* b_ih = (const float*)d_in[3];
  const float* b_hh = (const float*)d_in[4];
  const float* w_fc = (const float*)d_in[5];
  const float* b_fc = (const float*)d_in[6];
  float* out = (float*)d_out;

  const int B = out_size;          // 16384
  const int T = in_sizes[0] / B;   // 2048

  dim3 grid(B / MB), block(TPB);
  hipLaunchKernelGGL(lstm_solo, grid, block, 0, stream,
                     x, w_ih, w_hh, b_ih, b_hh, w_fc, b_fc, out, T);
}

// Round 13
// 1891.184 us; speedup vs baseline: 1.1169x; 1.1169x over previous
//
#include <hip/hip_runtime.h>
#include <cstdint>

typedef __attribute__((ext_vector_type(8))) short short8;
typedef __attribute__((ext_vector_type(4))) float f32x4;
typedef __attribute__((ext_vector_type(2))) float f32x2;

#define TPB  256
#define MB   16      // batch rows per block
#define HS   50      // hidden size
#define HSTR 72      // h row stride in halves (144B, 16B-aligned)
#define XSTR 68      // x row stride in u32 (272B, 16B-aligned)
#define L2E  1.4426950408889634f
#define L2E2 2.8853900817779268f

__device__ __forceinline__ float ex2(float x) {
#if __has_builtin(__builtin_amdgcn_exp2f)
  return __builtin_amdgcn_exp2f(x);
#else
  float r; asm("v_exp_f32 %0, %1" : "=v"(r) : "v"(x)); return r;
#endif
}
__device__ __forceinline__ float rcp_(float x) {
#if __has_builtin(__builtin_amdgcn_rcpf)
  return __builtin_amdgcn_rcpf(x);
#else
  float r; asm("v_rcp_f32 %0, %1" : "=v"(r) : "v"(x)); return r;
#endif
}
__device__ __forceinline__ unsigned short bf16_rne(float f) {
  unsigned r;
  asm("v_cvt_pk_bf16_f32 %0, %1, %2" : "=v"(r) : "v"(f), "v"(f));
  return (unsigned short)r;
}
__device__ __forceinline__ unsigned cvtpk2(float a, float b) {
  unsigned r;
  asm("v_cvt_pk_bf16_f32 %0, %1, %2" : "=v"(r) : "v"(a), "v"(b));
  return r;   // lo = a, hi = b
}
__device__ __forceinline__ float bf16f(unsigned short h) {
  union { unsigned u; float f; } v; v.u = ((unsigned)h) << 16; return v.f;
}
__device__ __forceinline__ unsigned packx(float f) {
  unsigned short hi = bf16_rne(f);
  unsigned short lo = bf16_rne(f - bf16f(hi));
  return (unsigned)hi | ((unsigned)lo << 16);
}
// column swizzle (identical helper on every read and write)
__device__ __forceinline__ int swcol(int row, int col) {
  return (((col >> 3) ^ ((row >> 2) & 3)) << 3) | (col & 7);
}

// Transposed GEMM per step: gates^T[256 n][16 b] = W[256 n][64 k] * hT[64 k][16 b]
//   A-operand = W fragments (static, registers); B-operand = h^T from LDS.
//   K layout (REAL LDS columns, no register injection):
//     k 0..49 = h(t-1); k50 = xv_hi; k51 = xv_lo; k52 = xv_hi; k53 = 1.0
//     (rewritten per step by wave-0 lanes<16 into hw, like the h-writes);
//     k54 = 1.0 (static, both buffers); k55..63 = 0 (zero-weighted).
//   W frag1 slots pair them: k50,k51=w_ih_hi, k52=w_ih_lo, k53=bias_hi,
//   k54=bias_lo. W rows prescaled by log2e (2*log2e for g-gate).
//   Gate-chunk rotation g=(wid+rho)&3 balances the light chunk across SIMDs.
//   Light wave (g==3): skip all-pad r=2,3 ELEM half; h-write only lhi==0
//   (j=48,49 b32) so pad lanes never touch live x/bias cols 50..54.
__global__ __launch_bounds__(TPB, 4)
void lstm_mfma13(const float* __restrict__ x,
                 const float* __restrict__ w_ih,
                 const float* __restrict__ w_hh,
                 const float* __restrict__ b_ih,
                 const float* __restrict__ b_hh,
                 const float* __restrict__ w_fc,
                 const float* __restrict__ b_fc,
                 float* __restrict__ out, int T)
{
  __shared__ __attribute__((aligned(16))) unsigned short hbuf[2][MB][HSTR];
  __shared__ __attribute__((aligned(16))) unsigned x_lds[2][MB][XSTR];

  const int tid  = threadIdx.x;
  const int wid  = tid >> 6;
  const int lane = tid & 63;
  const int l15  = lane & 15;
  const int lhi  = lane >> 4;      // 0..3
  const int b0   = blockIdx.x * MB;
  const int rho  = (blockIdx.x >> 8) & 3;
  const int g    = (wid + rho) & 3;   // j-chunk this wave owns
  const int j    = g * 16 + l15;      // W row this lane loads
  const bool jval  = (j < HS);
  const bool light = (g == 3);        // j=48..63: r=2,3 all-pad

  // ---- build static W-fragments (A-operand), hi-only + xv/bias slots ----
  short8 Wh[4][2];
  #pragma unroll
  for (int s = 0; s < 4; ++s) {
    const float sc = (s == 2) ? L2E2 : L2E;
    float wsc = 0.f, bsc = 0.f;
    if (jval) {
      int row = s * HS + j;
      wsc = w_ih[row] * sc;
      bsc = (b_ih[row] + b_hh[row]) * sc;
    }
    const unsigned short wh = bf16_rne(wsc);
    const unsigned short wl = bf16_rne(wsc - bf16f(wh));
    const unsigned short bh = bf16_rne(bsc);
    const unsigned short bl = bf16_rne(bsc - bf16f(bh));
    #pragma unroll
    for (int i = 0; i < 8; ++i) {           // frag 0: k = 0..31
      int k = lhi * 8 + i;
      Wh[s][0][i] = (short)(jval ? bf16_rne(w_hh[(s * HS + j) * HS + k] * sc) : 0);
    }
    #pragma unroll
    for (int i = 0; i < 8; ++i) {           // frag 1: k = 32..63
      int k = 32 + lhi * 8 + i;
      unsigned short hv = 0;
      if (jval) {
        if (k < HS)                  hv = bf16_rne(w_hh[(s * HS + j) * HS + k] * sc);
        else if (k == 50 || k == 51) hv = wh;
        else if (k == 52)            hv = wl;
        else if (k == 53)            hv = bh;
        else if (k == 54)            hv = bl;
      }
      Wh[s][1][i] = (short)hv;
    }
  }

  // loop-invariant LDS offsets (halves)
  const int keyr  = (l15 >> 2) & 3;
  const int offA0 = l15 * HSTR + ((lhi ^ keyr) << 3);
  const int offA1 = l15 * HSTR + (((lhi + 4) ^ keyr) << 3);
  // packed h-write: row b=l15, cols j_base..j_base+3, j_base = g*16 + lhi*4
  const int offW  = l15 * HSTR + ((((g * 2 + (lhi >> 1)) ^ keyr) << 3)) + (lhi & 1) * 4;
  // x/bias column block (cols 48..55) at row l15 (used by tid<16: row = tid)
  const int offX  = l15 * HSTR + ((6 ^ keyr) << 3);

  // ---- init LDS ----
  for (int idx = tid; idx < 2 * MB * HSTR; idx += TPB)
    (&hbuf[0][0][0])[idx] = 0;
  {
    // stage x chunk 0 (coalesced float4 -> packed hi/lo u32)
    int bb = tid >> 4, tt = (tid & 15) * 4;
    const f32x4 v = *(const f32x4*)(x + (size_t)(b0 + bb) * T + tt);
    uint4 up;
    up.x = packx(v[0]); up.y = packx(v[1]); up.z = packx(v[2]); up.w = packx(v[3]);
    *(uint4*)&x_lds[0][bb][tt] = up;
  }
  __syncthreads();
  if (tid < 16) {
    // k54 = 1.0 static in BOTH buffers; x(0) cols into hbuf[0]
    hbuf[0][0][offX + 6] = 0x3F80;   // offX is row-tid based (l15 == tid)
    hbuf[1][0][offX + 6] = 0x3F80;
    const unsigned xp0 = x_lds[0][tid][0];
    *(unsigned*)(&hbuf[0][0][0] + offX + 2) = xp0;                           // k50,51
    *(unsigned*)(&hbuf[0][0][0] + offX + 4) = (xp0 & 0xFFFFu) | 0x3F800000u; // k52,53
  }
  __syncthreads();

  // cell state carried scaled: c~ = 2*log2e*c ; rows r=0,1 in cA, r=2,3 in cB
  f32x2 cA = {0.f, 0.f}, cB = {0.f, 0.f};
  f32x4 xf = {0.f, 0.f, 0.f, 0.f};
  const int nch = T >> 6;   // T multiple of 64 (T=2048)

  // elementwise core (identical arithmetic to round-7/10 known-good)
  auto ELEM = [&](f32x2 ai, f32x2 af, f32x2 ag, f32x2 ao, f32x2& c2) -> f32x2 {
    f32x2 u, v, w, z, q, rD, r3, vm1;
    u[0] = ex2(-ai[0]); u[1] = ex2(-ai[1]);
    v[0] = ex2( ag[0]); v[1] = ex2( ag[1]);
    w[0] = ex2(-af[0]); w[1] = ex2(-af[1]);
    z[0] = ex2(-ao[0]); z[1] = ex2(-ao[1]);
    f32x2 t1 = (u + 1.f) * (v + 1.f);
    f32x2 wp = w + 1.f;
    f32x2 D  = t1 * wp;
    rD[0] = rcp_(D[0]); rD[1] = rcp_(D[1]);
    vm1[0] = fmaf(v[0], L2E2, -L2E2);
    vm1[1] = fmaf(v[1], L2E2, -L2E2);
    f32x2 num = c2 * t1 + vm1 * wp;
    f32x2 cn = num * rD;
    cn[0] = fminf(fmaxf(cn[0], -86.f), 86.f);
    cn[1] = fminf(fmaxf(cn[1], -86.f), 86.f);
    c2 = cn;
    q[0] = ex2(cn[0]); q[1] = ex2(cn[1]);
    f32x2 t3 = (z + 1.f) * (q + 1.f);
    r3[0] = rcp_(t3[0]); r3[1] = rcp_(t3[1]);
    return (q - 1.f) * r3;
  };

  // xpn = packed x for the NEXT step (t+1), written into hw's x-cols
  auto STEP = [&](const unsigned short* hr, unsigned short* hw, unsigned xpn) {
    const short8 B0 = *(const short8*)(hr + offA0);
    const short8 B1 = *(const short8*)(hr + offA1);

    __builtin_amdgcn_s_setprio(1);
    f32x4 acc[4];
    #pragma unroll
    for (int s = 0; s < 4; ++s) {
      acc[s] = __builtin_amdgcn_mfma_f32_16x16x32_bf16(Wh[s][0], B0,
                   (f32x4){0.f, 0.f, 0.f, 0.f}, 0, 0, 0);
      acc[s] = __builtin_amdgcn_mfma_f32_16x16x32_bf16(Wh[s][1], B1, acc[s], 0, 0, 0);
    }
    __builtin_amdgcn_s_setprio(0);

    // x(t+1)/bias cols into hw (same producer->barrier->consumer as h-writes)
    if (tid < 16) {
      *(unsigned*)(hw + offX + 2) = xpn;                              // k50,51
      *(unsigned*)(hw + offX + 4) = (xpn & 0xFFFFu) | 0x3F800000u;    // k52,53
    }

    f32x2 h2A = ELEM((f32x2){acc[0][0], acc[0][1]}, (f32x2){acc[1][0], acc[1][1]},
                     (f32x2){acc[2][0], acc[2][1]}, (f32x2){acc[3][0], acc[3][1]}, cA);
    unsigned hx = cvtpk2(h2A[0], h2A[1]);
    if (!light) {
      f32x2 h2B = ELEM((f32x2){acc[0][2], acc[0][3]}, (f32x2){acc[1][2], acc[1][3]},
                       (f32x2){acc[2][2], acc[2][3]}, (f32x2){acc[3][2], acc[3][3]}, cB);
      uint2 hwv;
      hwv.x = hx;
      hwv.y = cvtpk2(h2B[0], h2B[1]);
      *(uint2*)(hw + offW) = hwv;      // 4 consecutive j at row b=l15
    } else if (lhi == 0) {
      // light wave: only j=48,49 are real; lanes lhi>=1 MUST NOT write
      // (cols 50..54 now hold live x/bias data)
      *(unsigned*)(hw + offW) = hx;
    }

    __syncthreads();   // h(t), x(t+1) visible; everyone done reading hr
  };

  unsigned short* hb0 = &hbuf[0][0][0];
  unsigned short* hb1 = &hbuf[1][0][0];

  for (int ch = 0; ch < nch; ++ch) {
    const int par = ch & 1;
    const unsigned* xrow  = &x_lds[par][l15][0];      // lanes<16: row = tid
    const unsigned* xrowN = &x_lds[par ^ 1][l15][0];
    // packed x for step (chunk-local slot s); s==64 -> next chunk slot 0.
    auto XP = [&](int s) -> unsigned {
      unsigned r = 0;
      if (tid < 16) {
        const unsigned* p = (s < 64) ? xrow : xrowN;
        r = p[s & 63];
      }
      return r;
    };
    int slot = 0;
    #pragma unroll 1
    for (int i = 0; i < 8; ++i) {          // slots 0..15
      STEP(hb0, hb1, XP(slot + 1)); STEP(hb1, hb0, XP(slot + 2)); slot += 2;
    }
    if (ch + 1 < nch)                      // issue next-chunk global load (~slot 16)
      xf = *(const f32x4*)(x + (size_t)(b0 + (tid >> 4)) * T + (ch + 1) * 64 + (tid & 15) * 4);
    #pragma unroll 1
    for (int i = 0; i < 14; ++i) {         // slots 16..43
      STEP(hb0, hb1, XP(slot + 1)); STEP(hb1, hb0, XP(slot + 2)); slot += 2;
    }
    if (ch + 1 < nch) {                    // write next-chunk x to LDS (~slot 44)
      uint4 up;
      up.x = packx(xf[0]); up.y = packx(xf[1]);
      up.z = packx(xf[2]); up.w = packx(xf[3]);
      *(uint4*)&x_lds[par ^ 1][tid >> 4][(tid & 15) * 4] = up;
    }
    #pragma unroll 1
    for (int i = 0; i < 10; ++i) {         // slots 44..63 (last XP(64) -> xrowN[0])
      STEP(hb0, hb1, XP(slot + 1)); STEP(hb1, hb0, XP(slot + 2)); slot += 2;
    }
  }

  // fc head on final h (T even -> final h in hbuf[0]; cols >=50 hold x/bias)
  if (tid < MB) {
    const unsigned short* hfin = hb0 + tid * HSTR;
    float s = 0.f;
    for (int jj = 0; jj < HS; ++jj)
      s = fmaf(bf16f(hfin[swcol(tid, jj)]), w_fc[jj], s);
    out[b0 + tid] = s + b_fc[0];
  }
}

extern "C" void kernel_launch(void* const* d_in, const int* in_sizes, int n_in,
                              void* d_out, int out_size, void* d_ws, size_t ws_size,
                              hipStream_t stream) {
  const float* x    = (const float*)d_in[0];
  const float* w_ih = (const float*)d_in[1];
  const float* w_hh = (const float*)d_in[2];
  const float* b_ih = (const float*)d_in[3];
  const float* b_hh = (const float*)d_in[4];
  const float* w_fc = (const float*)d_in[5];
  const float* b_fc = (const float*)d_in[6];
  float* out = (float*)d_out;

  const int B = out_size;          // 16384
  const int T = in_sizes[0] / B;   // 2048

  dim3 grid(B / MB), block(TPB);
  hipLaunchKernelGGL(lstm_mfma13, grid, block, 0, stream,
                     x, w_ih, w_hh, b_ih, b_hh, w_fc, b_fc, out, T);
}